// Round 2
// baseline (13341.165 us; speedup 1.0000x reference)
//
#include <hip/hip_runtime.h>
#include <hip/hip_bf16.h>

// Problem: S=48, T=32, B=64, H=1024, E=512, V=32000, PAD=1
// 3H=3072, 2H=2048, 2H+E=2560, 3H+E=3584, decoder steps = T-1 = 31
// Inputs/outputs are float32 (per reference). Heavy GEMMs convert to bf16
// internally for MFMA; recurrence math stays fp32.

using bf16x8 = __attribute__((ext_vector_type(8))) short;
using f32x4  = __attribute__((ext_vector_type(4))) float;
typedef __hip_bfloat16 bf16;

#define SS 48
#define TT 32
#define BB 64
#define HH 1024
#define EE 512
#define VV 32000

__device__ __forceinline__ short f2bs(float x) {
  return __builtin_bit_cast(short, __float2bfloat16(x));
}

// ---------------------------------------------------------------------------
// Embedding gather + fp32->bf16: emb_bf[(s*B+b)*E+e] = bf16(emb_enc[src[s*B+b]*E+e])
// ---------------------------------------------------------------------------
__global__ __launch_bounds__(256) void embed_src(
    const int* __restrict__ src, const float* __restrict__ emb_enc,
    bf16* __restrict__ emb_bf)
{
  int f = blockIdx.x * 256 + threadIdx.x;   // 196608 frags of 8
  int row = f >> 6;                          // E/8 = 64 frags per row
  int e8 = (f & 63) * 8;
  int tok = src[row];
  const float* p = emb_enc + (size_t)tok * EE + e8;
  float4 a = *(const float4*)p;
  float4 b = *(const float4*)(p + 4);
  bf16x8 v;
  v[0] = f2bs(a.x); v[1] = f2bs(a.y); v[2] = f2bs(a.z); v[3] = f2bs(a.w);
  v[4] = f2bs(b.x); v[5] = f2bs(b.y); v[6] = f2bs(b.z); v[7] = f2bs(b.w);
  *(bf16x8*)((short*)emb_bf + (size_t)row * EE + e8) = v;
}

// ---------------------------------------------------------------------------
// MFMA bf16 GEMM:  C[M,N] = A[M,K](bf16) @ W[N,K](fp32->bf16)^T (+bias fp32)
// 128x128 tile, BK=32, 4 waves (2x2), each wave 4x4 mfma 16x16x32 tiles.
// LDS row stride 40 bf16 (breaks the b128 bank conflict).
// Layouts (verified m89): A-frag A[m=lane&15][k=quad*8+j];
// B-frag B[k=quad*8+j][n=lane&15]; D: col=lane&15, row=quad*4+reg.
// ---------------------------------------------------------------------------
__global__ __launch_bounds__(256) void gemm_mfma(
    const bf16* __restrict__ A, int lda,
    const float* __restrict__ W, int ldw,
    const float* __restrict__ bias,
    float* __restrict__ C, int ldc,
    int K, int Mstore)
{
  __shared__ __align__(16) short sA[128 * 40];
  __shared__ __align__(16) short sB[128 * 40];
  const int tid = threadIdx.x;
  const int m0 = blockIdx.y * 128;
  const int n0 = blockIdx.x * 128;
  const int lane = tid & 63;
  const int wave = tid >> 6;
  const int wr = wave >> 1, wc = wave & 1;
  const int quad = lane >> 4, l15 = lane & 15;

  f32x4 acc[4][4];
#pragma unroll
  for (int i = 0; i < 4; i++)
#pragma unroll
    for (int j = 0; j < 4; j++) acc[i][j] = f32x4{0.f, 0.f, 0.f, 0.f};

  const short* Ag = (const short*)A;

  for (int k0 = 0; k0 < K; k0 += 32) {
#pragma unroll
    for (int f = 0; f < 2; f++) {
      int idx = tid + f * 256;          // 0..511 slots (128 rows x 4 col-groups)
      int r = idx >> 2, cg = idx & 3;
      bf16x8 va = *(const bf16x8*)(Ag + (size_t)(m0 + r) * lda + k0 + cg * 8);
      *(bf16x8*)&sA[r * 40 + cg * 8] = va;
      const float* wp = W + (size_t)(n0 + r) * ldw + k0 + cg * 8;
      float4 w0 = *(const float4*)wp;
      float4 w1 = *(const float4*)(wp + 4);
      bf16x8 vb;
      vb[0] = f2bs(w0.x); vb[1] = f2bs(w0.y); vb[2] = f2bs(w0.z); vb[3] = f2bs(w0.w);
      vb[4] = f2bs(w1.x); vb[5] = f2bs(w1.y); vb[6] = f2bs(w1.z); vb[7] = f2bs(w1.w);
      *(bf16x8*)&sB[r * 40 + cg * 8] = vb;
    }
    __syncthreads();
    bf16x8 af[4], bfr[4];
#pragma unroll
    for (int i = 0; i < 4; i++)
      af[i] = *(const bf16x8*)&sA[(wr * 64 + i * 16 + l15) * 40 + quad * 8];
#pragma unroll
    for (int j = 0; j < 4; j++)
      bfr[j] = *(const bf16x8*)&sB[(wc * 64 + j * 16 + l15) * 40 + quad * 8];
#pragma unroll
    for (int i = 0; i < 4; i++)
#pragma unroll
      for (int j = 0; j < 4; j++)
        acc[i][j] = __builtin_amdgcn_mfma_f32_16x16x32_bf16(af[i], bfr[j], acc[i][j], 0, 0, 0);
    __syncthreads();
  }

#pragma unroll
  for (int i = 0; i < 4; i++) {
#pragma unroll
    for (int j = 0; j < 4; j++) {
#pragma unroll
      for (int r = 0; r < 4; r++) {
        int m = m0 + wr * 64 + i * 16 + quad * 4 + r;
        int n = n0 + wc * 64 + j * 16 + l15;
        if (m < Mstore) {
          float v = acc[i][j][r];
          if (bias) v += bias[n];
          C[(size_t)m * ldc + n] = v;
        }
      }
    }
  }
}

// ---------------------------------------------------------------------------
// fp32 tiled GEMM (64x64 tile, 4x4 micro, K-chunk 16) with split-K support:
//   p = blockIdx.z computes A[:, p*Klen:(p+1)*Klen] @ W^T into C + p*csplit.
// ---------------------------------------------------------------------------
__global__ __launch_bounds__(256) void gemm64(
    const float* __restrict__ A, int lda,
    const float* __restrict__ W, int ldw,
    const float* __restrict__ bias,
    float* __restrict__ C, long long csplit, int ldc,
    int M, int Klen)
{
  __shared__ __align__(16) float As[64][20];
  __shared__ __align__(16) float Ws[64][20];
  const int tid = threadIdx.x;
  const int tx = tid & 15, ty = tid >> 4;
  const int n0 = blockIdx.x * 64;
  const int m0 = blockIdx.y * 64;
  const int kbeg = blockIdx.z * Klen;
  float acc[4][4] = {};

  for (int k0 = kbeg; k0 < kbeg + Klen; k0 += 16) {
#pragma unroll
    for (int i = 0; i < 4; i++) {
      int idx = tid + i * 256;          // 0..1023 : 64 rows x 16 cols
      int r = idx >> 4, c = idx & 15;
      int m = m0 + r;
      As[r][c] = (m < M) ? A[(size_t)m * lda + k0 + c] : 0.f;
      Ws[r][c] = W[(size_t)(n0 + r) * ldw + k0 + c];
    }
    __syncthreads();
#pragma unroll
    for (int kk = 0; kk < 16; kk += 4) {
      float4 a4[4], w4[4];
#pragma unroll
      for (int i = 0; i < 4; i++) a4[i] = *(const float4*)&As[ty + 16 * i][kk];
#pragma unroll
      for (int j = 0; j < 4; j++) w4[j] = *(const float4*)&Ws[tx + 16 * j][kk];
#pragma unroll
      for (int i = 0; i < 4; i++)
#pragma unroll
        for (int j = 0; j < 4; j++) {
          acc[i][j] += a4[i].x * w4[j].x;
          acc[i][j] += a4[i].y * w4[j].y;
          acc[i][j] += a4[i].z * w4[j].z;
          acc[i][j] += a4[i].w * w4[j].w;
        }
    }
    __syncthreads();
  }

  float* Cp = C + (size_t)blockIdx.z * csplit;
#pragma unroll
  for (int i = 0; i < 4; i++) {
    int m = m0 + ty + 16 * i;
    if (m >= M) continue;
#pragma unroll
    for (int j = 0; j < 4; j++) {
      int n = n0 + tx + 16 * j;
      float v = acc[i][j];
      if (bias) v += bias[n];
      Cp[(size_t)m * ldc + n] = v;
    }
  }
}

// ---------------------------------------------------------------------------
__device__ __forceinline__ float sigmoidf_(float x) { return 1.f / (1.f + expf(-x)); }

// Encoder GRU elementwise (both directions fused).
__global__ __launch_bounds__(256) void gru_enc(
    const float* __restrict__ gx_f, const float* __restrict__ gx_b,
    const float* __restrict__ ghf_p, const float* __restrict__ ghb_p,
    const float* __restrict__ bh_f, const float* __restrict__ bh_b,
    float* __restrict__ h_f, float* __restrict__ h_b,
    float* __restrict__ enc, float* __restrict__ hcat, int s)
{
  int idx = blockIdx.x * 256 + threadIdx.x;   // 2*B*H = 131072
  int dir = idx >> 16;
  int r = idx & 65535;
  int b = r >> 10, j = r & 1023;
  const float* gx = dir ? gx_b : gx_f;
  const float* ghp = dir ? ghb_p : ghf_p;
  const float* bh = dir ? bh_b : bh_f;
  float* h = dir ? h_b : h_f;
  int so = dir ? (SS - 1 - s) : s;

  const float* gxr = gx + ((size_t)so * BB + b) * 3072;
  const int base = b * 3072 + j;
  const int P = BB * 3072;
  float hr = ghp[base] + ghp[P + base] + ghp[2 * P + base] + ghp[3 * P + base] + bh[j];
  float hz = ghp[base + 1024] + ghp[P + base + 1024] + ghp[2 * P + base + 1024] + ghp[3 * P + base + 1024] + bh[1024 + j];
  float hn = ghp[base + 2048] + ghp[P + base + 2048] + ghp[2 * P + base + 2048] + ghp[3 * P + base + 2048] + bh[2048 + j];
  float rg = sigmoidf_(gxr[j] + hr);
  float zg = sigmoidf_(gxr[1024 + j] + hz);
  float ng = tanhf(gxr[2048 + j] + rg * hn);
  float hprev = h[b * HH + j];
  float hnew = (1.f - zg) * ng + zg * hprev;
  h[b * HH + j] = hnew;
  enc[((size_t)b * SS + so) * 2048 + dir * 1024 + j] = hnew;
  if (s == SS - 1) hcat[b * 2048 + dir * 1024 + j] = hnew;
}

// hidden = tanh(sum_p hp + b_fc)
__global__ __launch_bounds__(256) void combine_hidden(
    const float* __restrict__ hp, const float* __restrict__ b_fc,
    float* __restrict__ h_dec)
{
  int idx = blockIdx.x * 256 + threadIdx.x;  // B*H = 65536
  int j = idx & 1023;
  const int P = BB * HH;
  h_dec[idx] = tanhf(hp[idx] + hp[P + idx] + hp[2 * P + idx] + hp[3 * P + idx] + b_fc[j]);
}

// ---------------------------------------------------------------------------
// Attention step: scores -> masked softmax -> context w; writes dec_in=[et,w]
// (fp32) and feat[t] w/et parts (bf16, for deferred output projection).
// ---------------------------------------------------------------------------
__global__ __launch_bounds__(256) void attn_step(
    const float* __restrict__ dpp,        // 4 partials of h@W_attn_h^T, (B,H)
    const float* __restrict__ enc_proj,   // (B,S,H)  enc@W_attn_enc^T + b_attn
    const float* __restrict__ v_attn,
    const float* __restrict__ enc,        // (B,S,2H)
    const int* __restrict__ src,
    const int* __restrict__ trg,
    const float* __restrict__ emb_dec,
    int t,
    float* __restrict__ dec_in,           // (B, E+2H)
    bf16* __restrict__ feat)              // rows t*B.., ld 3584
{
  __shared__ float dp[1024];
  __shared__ float sc[SS];
  __shared__ float aw[SS];
  const int b = blockIdx.x;
  const int tid = threadIdx.x;
  const int P = BB * HH;
  for (int j = tid; j < 1024; j += 256)
    dp[j] = dpp[b * HH + j] + dpp[P + b * HH + j] + dpp[2 * P + b * HH + j] + dpp[3 * P + b * HH + j];
  __syncthreads();

  const int lane = tid & 63, w = tid >> 6;
  for (int s = w; s < SS; s += 4) {
    float p = 0.f;
    const float* ep = enc_proj + ((size_t)b * SS + s) * HH;
    for (int j = lane; j < 1024; j += 64)
      p += tanhf(dp[j] + ep[j]) * v_attn[j];
#pragma unroll
    for (int off = 32; off; off >>= 1) p += __shfl_down(p, off);
    if (lane == 0) sc[s] = p;
  }
  __syncthreads();

  if (tid < 64) {
    float v = -3.0e38f;
    if (tid < SS) v = (src[tid * BB + b] != 1) ? sc[tid] : -1.0e10f;
    float mx = v;
#pragma unroll
    for (int off = 32; off; off >>= 1) mx = fmaxf(mx, __shfl_xor(mx, off));
    float e = (tid < SS) ? expf(v - mx) : 0.f;
    float sum = e;
#pragma unroll
    for (int off = 32; off; off >>= 1) sum += __shfl_xor(sum, off);
    if (tid < SS) aw[tid] = e / sum;
  }
  __syncthreads();

  bf16* frow = feat + ((size_t)t * BB + b) * 3584;
  for (int k = tid; k < 2048; k += 256) {
    float acc = 0.f;
    const float* er = enc + ((size_t)b * SS) * 2048 + k;
#pragma unroll 4
    for (int s = 0; s < SS; s++) acc += aw[s] * er[(size_t)s * 2048];
    dec_in[b * 2560 + 512 + k] = acc;
    frow[1024 + k] = __float2bfloat16(acc);
  }
  const int tok = trg[t * BB + b];
  for (int e = tid; e < 512; e += 256) {
    float ev = emb_dec[(size_t)tok * EE + e];
    dec_in[b * 2560 + e] = ev;
    frow[3072 + e] = __float2bfloat16(ev);
  }
}

// Decoder GRU elementwise.
__global__ __launch_bounds__(256) void gru_dec(
    const float* __restrict__ gxp, const float* __restrict__ ghp,
    const float* __restrict__ bi, const float* __restrict__ bh,
    float* __restrict__ h, bf16* __restrict__ feat, int t)
{
  int idx = blockIdx.x * 256 + threadIdx.x;   // B*H = 65536
  int b = idx >> 10, j = idx & 1023;
  const int base = b * 3072 + j;
  const int P = BB * 3072;
  float xr = gxp[base] + gxp[P + base] + gxp[2 * P + base] + gxp[3 * P + base] + bi[j];
  float xz = gxp[base + 1024] + gxp[P + base + 1024] + gxp[2 * P + base + 1024] + gxp[3 * P + base + 1024] + bi[1024 + j];
  float xn = gxp[base + 2048] + gxp[P + base + 2048] + gxp[2 * P + base + 2048] + gxp[3 * P + base + 2048] + bi[2048 + j];
  float hr = ghp[base] + ghp[P + base] + ghp[2 * P + base] + ghp[3 * P + base] + bh[j];
  float hz = ghp[base + 1024] + ghp[P + base + 1024] + ghp[2 * P + base + 1024] + ghp[3 * P + base + 1024] + bh[1024 + j];
  float hn = ghp[base + 2048] + ghp[P + base + 2048] + ghp[2 * P + base + 2048] + ghp[3 * P + base + 2048] + bh[2048 + j];
  float rg = sigmoidf_(xr + hr);
  float zg = sigmoidf_(xz + hz);
  float ng = tanhf(xn + rg * hn);
  float hprev = h[idx];
  float hnew = (1.f - zg) * ng + zg * hprev;
  h[idx] = hnew;
  feat[((size_t)t * BB + b) * 3584 + j] = __float2bfloat16(hnew);
}

// ---------------------------------------------------------------------------
extern "C" void kernel_launch(void* const* d_in, const int* in_sizes, int n_in,
                              void* d_out, int out_size, void* d_ws, size_t ws_size,
                              hipStream_t stream)
{
  const int* src = (const int*)d_in[0];
  const int* trg = (const int*)d_in[1];
  const float* emb_enc = (const float*)d_in[2];
  const float* Wi_f = (const float*)d_in[3];
  const float* Wh_f = (const float*)d_in[4];
  const float* bi_f = (const float*)d_in[5];
  const float* bh_f = (const float*)d_in[6];
  const float* Wi_b = (const float*)d_in[7];
  const float* Wh_b = (const float*)d_in[8];
  const float* bi_b = (const float*)d_in[9];
  const float* bh_b = (const float*)d_in[10];
  const float* W_fc = (const float*)d_in[11];
  const float* b_fc = (const float*)d_in[12];
  const float* W_attn = (const float*)d_in[13];
  const float* b_attn = (const float*)d_in[14];
  const float* v_attn = (const float*)d_in[15];
  const float* emb_dec = (const float*)d_in[16];
  const float* Wi_d = (const float*)d_in[17];
  const float* Wh_d = (const float*)d_in[18];
  const float* bi_d = (const float*)d_in[19];
  const float* bh_d = (const float*)d_in[20];
  const float* W_out = (const float*)d_in[21];
  const float* b_out = (const float*)d_in[22];
  float* out = (float*)d_out;

  // workspace layout (~148 MB total)
  size_t off = 0;
  auto alloc = [&](size_t bytes) {
    void* r = (char*)d_ws + off;
    off += (bytes + 255) & ~(size_t)255;
    return r;
  };
  bf16* emb_bf   = (bf16*)alloc((size_t)SS * BB * EE * 2);
  float* gx_f    = (float*)alloc((size_t)SS * BB * 3072 * 4);
  float* gx_b    = (float*)alloc((size_t)SS * BB * 3072 * 4);
  float* ghf_p   = (float*)alloc((size_t)4 * BB * 3072 * 4);
  float* ghb_p   = (float*)alloc((size_t)4 * BB * 3072 * 4);
  float* h_f     = (float*)alloc((size_t)BB * HH * 4);
  float* h_b     = (float*)alloc((size_t)BB * HH * 4);
  float* enc     = (float*)alloc((size_t)BB * SS * 2048 * 4);
  float* hcat    = (float*)alloc((size_t)BB * 2048 * 4);
  float* hp      = (float*)alloc((size_t)4 * BB * HH * 4);
  float* h_dec   = (float*)alloc((size_t)BB * HH * 4);
  float* enc_proj= (float*)alloc((size_t)BB * SS * HH * 4);
  float* dpp     = (float*)alloc((size_t)4 * BB * HH * 4);
  float* dec_in  = (float*)alloc((size_t)BB * 2560 * 4);
  float* gxdp    = (float*)alloc((size_t)4 * BB * 3072 * 4);
  float* ghdp    = (float*)alloc((size_t)4 * BB * 3072 * 4);
  bf16* feat     = (bf16*)alloc((size_t)2048 * 3584 * 2);  // padded to M=2048

  hipMemsetAsync(h_f, 0, (size_t)BB * HH * 4, stream);
  hipMemsetAsync(h_b, 0, (size_t)BB * HH * 4, stream);
  hipMemsetAsync(d_out, 0, (size_t)BB * VV * 4, stream);  // output row t=0 = zeros

  // --- encoder input GEMMs (MFMA): gx = emb @ Wi^T + bi  (3072x3072xK=512)
  embed_src<<<768, 256, 0, stream>>>(src, emb_enc, emb_bf);
  gemm_mfma<<<dim3(24, 24), 256, 0, stream>>>(emb_bf, 512, Wi_f, 512, bi_f, gx_f, 3072, 512, 3072);
  gemm_mfma<<<dim3(24, 24), 256, 0, stream>>>(emb_bf, 512, Wi_b, 512, bi_b, gx_b, 3072, 512, 3072);

  // --- encoder recurrence (48 steps, fwd+bwd)
  for (int s = 0; s < SS; s++) {
    gemm64<<<dim3(48, 1, 4), 256, 0, stream>>>(h_f, 1024, Wh_f, 1024, nullptr, ghf_p, (long long)BB * 3072, 3072, 64, 256);
    gemm64<<<dim3(48, 1, 4), 256, 0, stream>>>(h_b, 1024, Wh_b, 1024, nullptr, ghb_p, (long long)BB * 3072, 3072, 64, 256);
    gru_enc<<<512, 256, 0, stream>>>(gx_f, gx_b, ghf_p, ghb_p, bh_f, bh_b, h_f, h_b, enc, hcat, s);
  }

  // --- hidden = tanh([hf,hb] @ W_fc^T + b_fc)
  gemm64<<<dim3(16, 1, 4), 256, 0, stream>>>(hcat, 2048, W_fc, 2048, nullptr, hp, (long long)BB * HH, 1024, 64, 512);
  combine_hidden<<<256, 256, 0, stream>>>(hp, b_fc, h_dec);

  // --- step-invariant attention precompute: enc_proj = enc @ W_attn[:,H:]^T + b_attn
  gemm64<<<dim3(16, 48, 1), 256, 0, stream>>>(enc, 2048, W_attn + 1024, 3072, b_attn, enc_proj, 0, 1024, 3072, 2048);

  // --- decoder recurrence (31 steps); output projection deferred
  for (int t = 0; t < TT - 1; t++) {
    gemm64<<<dim3(16, 1, 4), 256, 0, stream>>>(h_dec, 1024, W_attn, 3072, nullptr, dpp, (long long)BB * HH, 1024, 64, 256);
    attn_step<<<64, 256, 0, stream>>>(dpp, enc_proj, v_attn, enc, src, trg, emb_dec, t, dec_in, feat);
    gemm64<<<dim3(48, 1, 4), 256, 0, stream>>>(dec_in, 2560, Wi_d, 2560, nullptr, gxdp, (long long)BB * 3072, 3072, 64, 640);
    gemm64<<<dim3(48, 1, 4), 256, 0, stream>>>(h_dec, 1024, Wh_d, 1024, nullptr, ghdp, (long long)BB * 3072, 3072, 64, 256);
    gru_dec<<<256, 256, 0, stream>>>(gxdp, ghdp, bi_d, bh_d, h_dec, feat, t);
  }

  // --- batched output projection: (31*64=1984) x 32000 x 3584, fp32 out
  gemm_mfma<<<dim3(250, 16), 256, 0, stream>>>(feat, 3584, W_out, 3584, b_out,
                                               out + (size_t)BB * VV, VV, 3584, 1984);
}